// Round 4
// baseline (756.944 us; speedup 1.0000x reference)
//
#include <hip/hip_runtime.h>
#include <math.h>

typedef __attribute__((ext_vector_type(8))) short short8_t;
typedef __attribute__((ext_vector_type(4))) float f32x4;

#define Hh 512
#define Ww 512
#define IMG (Hh * Ww)
#define WINP 128
#define NPX 16384
#define AST 40    // s_a pixel stride (shorts), 80B = 5*16B aligned
#define H1ST 72   // s_h1/s_h2 pixel stride (shorts), 144B = 9*16B aligned

__device__ __forceinline__ unsigned short f2bf(float f) {
    unsigned int u = __builtin_bit_cast(unsigned int, f);
    u += 0x7fffu + ((u >> 16) & 1u);
    return (unsigned short)(u >> 16);
}
__device__ __forceinline__ float bf2f(unsigned short h) {
    unsigned int u = ((unsigned int)h) << 16;
    return __builtin_bit_cast(float, u);
}

// ---------------- box (argmax) ----------------
__global__ void box_kernel(const float* __restrict__ pred, int* __restrict__ box) {
    int tid = threadIdx.x;
    float best = -1.0f; int bidx = 0x7fffffff;
    for (int cand = tid; cand < 51 * 51; cand += 256) {
        int i = cand / 51, j = cand % 51;
        int y = i * 10, x = j * 10;
        float T = 0.f, Bv = 0.f;
#pragma unroll
        for (int k = 0; k < 6; ++k) {
            T  += pred[((k * 3 + 0) * Hh + y) * Ww + x];
            Bv += pred[((k * 3 + 2) * Hh + y) * Ww + x];
        }
        float d = fabsf(1.0f - T - Bv / 6.0f);
        if (d > best || (d == best && cand < bidx)) { best = d; bidx = cand; }
    }
    __shared__ float sv[256];
    __shared__ int   si[256];
    sv[tid] = best; si[tid] = bidx;
    __syncthreads();
    for (int s = 128; s > 0; s >>= 1) {
        if (tid < s) {
            if (sv[tid + s] > sv[tid] || (sv[tid + s] == sv[tid] && si[tid + s] < si[tid])) {
                sv[tid] = sv[tid + s]; si[tid] = si[tid + s];
            }
        }
        __syncthreads();
    }
    if (tid == 0) {
        int idx = si[0];
        int cy = (idx / 51) * 10, cx = (idx % 51) * 10;
        int yy = cy - 64; yy = yy < 0 ? 0 : (yy > Hh - WINP ? Hh - WINP : yy);
        int xx = cx - 64; xx = xx < 0 ? 0 : (xx > Ww - WINP ? Ww - WINP : xx);
        box[0] = yy; box[1] = xx;
    }
}

// ---------------- weight swizzle (B-fragment order), same mapping as round 3 ----
__device__ __forceinline__ void weights_body(int idx, const float* sw, const float* m1w,
                                             const float* m2w, const float* hw,
                                             unsigned short* WF)
{
    int j = idx & 7;
    int lane = (idx >> 3) & 63;
    int frag = idx >> 9;
    int n16 = lane & 15;
    int ko = (lane >> 4) * 8 + j;
    float v = 0.f;
    if (frag < 108) {
        int g = frag / 36; int r = frag % 36; int kc = r / 18; r %= 18; int tap = r / 2; int nf = r & 1;
        int oc = g * 32 + nf * 16 + n16; int ic = kc * 32 + ko;
        v = sw[(oc * 64 + ic) * 9 + tap];
    } else if (frag < 252) {
        int r = frag - 108; int half = r / 72; r %= 72; int kc = r / 18; r %= 18; int tap = r / 2; int nf = r & 1;
        int oc = half * 32 + nf * 16 + n16; int ic = kc * 32 + ko;
        if (ic < 99) v = m1w[(oc * 99 + ic) * 9 + tap];
    } else if (frag < 324) {
        int r = frag - 252; int half = r / 36; r %= 36; int kc = r / 18; r %= 18; int tap = r / 2; int nf = r & 1;
        int oc = half * 32 + nf * 16 + n16; int ic = kc * 32 + ko;
        v = m2w[(oc * 64 + ic) * 9 + tap];
    } else {
        int r = frag - 324; int kc = r / 9; int tap = r % 9;
        int ic = kc * 32 + ko;
        if (n16 < 3) v = hw[(n16 * 64 + ic) * 9 + tap];
    }
    WF[idx] = f2bf(v);
}

// ---------------- modulate: msplit[(plane*2+kc)*NPX+px][32] = bf16(feat*pred) ----
__device__ __forceinline__ void modulate_body(int idx, const float* feat, const float* pl,
                                              const int* box, unsigned short* msplit)
{
    int q = idx & 7;                       // 8 ch-chunks of 8 (ic = q*8..q*8+7)
    int px = (idx >> 3) & (NPX - 1);
    int plane = idx >> 17;                 // 0..17 = k*3+g
    int k = plane / 3, g = plane % 3;
    int y1 = box[0], x1 = box[1];
    int py = px >> 7, pxc = px & 127;
    size_t goff = (size_t)(y1 + py) * Ww + x1 + pxc;
    float pv = pl[(size_t)(k * 3 + g) * IMG + goff];
    const float* fb = feat + (size_t)k * 64 * IMG + goff;
    short8_t o;
#pragma unroll
    for (int e = 0; e < 8; ++e)
        o[e] = (short)f2bf(fb[(size_t)(q * 8 + e) * IMG] * pv);
    int kc = q >> 2, ql = q & 3;
    *(short8_t*)&msplit[((size_t)(plane * 2 + kc) * NPX + px) * 32 + ql * 8] = o;
}

__global__ void modulate_kernel(const float* __restrict__ feat, const float* __restrict__ pl,
                                const int* __restrict__ box, unsigned short* __restrict__ msplit)
{
    modulate_body(blockIdx.x * 256 + threadIdx.x, feat, pl, box, msplit);
}

// ---------------- prep_all: weights | copy pred->out | modulate iter-0 ----------
__global__ void prep_all(const float* __restrict__ sw, const float* __restrict__ m1w,
                         const float* __restrict__ m2w, const float* __restrict__ hw,
                         unsigned short* __restrict__ WF,
                         const float4* __restrict__ pred4, float4* __restrict__ out4,
                         const float* __restrict__ feat, const float* __restrict__ pred,
                         const int* __restrict__ box, unsigned short* __restrict__ msplit)
{
    int b = blockIdx.x, t = threadIdx.x;
    if (b < 684) {
        weights_body(b * 256 + t, sw, m1w, m2w, hw, WF);
    } else if (b < 5292) {
        int i = (b - 684) * 256 + t;
        out4[i] = pred4[i];
    } else {
        modulate_body((b - 5292) * 256 + t, feat, pred, box, msplit);
    }
}

// ---------------- split conv MFMA: 32x16 tile, 512 thr, 8 waves -----------------
__global__ __launch_bounds__(512, 4) void split_mfma(
    const unsigned short* __restrict__ msplit, const unsigned short* __restrict__ WF,
    const float* __restrict__ sb, unsigned short* __restrict__ fscl)
{
    const int tid = threadIdx.x;
    const int l = tid & 63, w = tid >> 6;
    const int T = blockIdx.x;             // 32 tiles: 4 row x 8 col
    const int plane = blockIdx.y;         // 18 = k*3+g
    const int k = plane / 3, g = plane % 3;
    const int ty0 = (T >> 3) * 32, tx0 = (T & 7) * 16;

    __shared__ __align__(16) unsigned short s_a[612 * AST];   // 34x18 px
    __shared__ __align__(16) unsigned short s_b[18 * 512];

    f32x4 acc[4][2];
#pragma unroll
    for (int mf = 0; mf < 4; ++mf)
#pragma unroll
        for (int nf = 0; nf < 2; ++nf) acc[mf][nf] = (f32x4){0.f, 0.f, 0.f, 0.f};

    const int colb = l & 15, qo = (l >> 4) * 8;

    for (int kc = 0; kc < 2; ++kc) {
        __syncthreads();
        const unsigned short* msp = msplit + (size_t)(plane * 2 + kc) * NPX * 32;
        for (int u = tid; u < 2448; u += 512) {
            int pxs = u >> 2, q = u & 3;
            int r = pxs / 18, c = pxs - r * 18;
            int py = ty0 - 1 + r, px = tx0 - 1 + c;
            short8_t o;
            if (py >= 0 && py < WINP && px >= 0 && px < WINP) {
                o = *(const short8_t*)&msp[(size_t)(py * WINP + px) * 32 + q * 8];
            } else {
#pragma unroll
                for (int e = 0; e < 8; ++e) o[e] = 0;
            }
            *(short8_t*)&s_a[pxs * AST + q * 8] = o;
        }
        {
            const unsigned short* src = WF + (size_t)((g * 2 + kc) * 18) * 512;
            for (int u = tid; u < 1152; u += 512)
                *(short8_t*)&s_b[u * 8] = *(const short8_t*)&src[u * 8];
        }
        __syncthreads();
#pragma unroll
        for (int dx = 0; dx < 3; ++dx) {
            short8_t a6[6];
#pragma unroll
            for (int i = 0; i < 6; ++i)
                a6[i] = *(const short8_t*)&s_a[((w * 4 + i) * 18 + colb + dx) * AST + qo];
#pragma unroll
            for (int dy = 0; dy < 3; ++dy)
#pragma unroll
            for (int nf = 0; nf < 2; ++nf) {
                short8_t b = *(const short8_t*)&s_b[(((dy * 3 + dx) * 2 + nf) * 64 + l) * 8];
#pragma unroll
                for (int mf = 0; mf < 4; ++mf)
                    acc[mf][nf] = __builtin_amdgcn_mfma_f32_16x16x32_bf16(a6[mf + dy], b, acc[mf][nf], 0, 0, 0);
            }
        }
    }
    __syncthreads();
    unsigned short* s_t = s_a;   // 512px * 32ch = 16384 <= 24480
#pragma unroll
    for (int nf = 0; nf < 2; ++nf) {
        float bias = sb[g * 32 + nf * 16 + (l & 15)];
#pragma unroll
        for (int mf = 0; mf < 4; ++mf) {
            int row = w * 4 + mf;
#pragma unroll
            for (int r = 0; r < 4; ++r) {
                int colpx = (l >> 4) * 4 + r;
                s_t[(row * 16 + colpx) * 32 + nf * 16 + (l & 15)] = f2bf(acc[mf][nf][r] + bias);
            }
        }
    }
    __syncthreads();
    {
        int row = tid >> 4, col = tid & 15;
        size_t gpx = (size_t)(ty0 + row) * WINP + tx0 + col;
        unsigned short* dst = fscl + ((size_t)k * NPX + gpx) * 96 + g * 32;
#pragma unroll
        for (int i = 0; i < 4; ++i)
            *(short8_t*)&dst[i * 8] = *(short8_t*)&s_t[tid * 32 + i * 8];
    }
}

// ---------------- combine: fscl -> fcat (kc-planar, fully materialized) ---------
// fcat[(kc*6+k)*NPX + px][32]: kc0=T0+2f0, kc1=S0-f0+f1, kc2=S2/6, kc3=x+zeros
__global__ void combine_kernel(const unsigned short* __restrict__ fscl,
                               const float* __restrict__ x, const int* __restrict__ box,
                               unsigned short* __restrict__ fcat)
{
    const int tid = threadIdx.x;
    const int px0 = blockIdx.x * 64;
    const int y1 = box[0], x1 = box[1];
    __shared__ float s_S[64 * 96];

    {
        int px_l = tid >> 2, q = tid & 3;
        int px = px0 + px_l;
        float s0[8], s1[8], s2[8];
#pragma unroll
        for (int e = 0; e < 8; ++e) { s0[e] = 0.f; s1[e] = 0.f; s2[e] = 0.f; }
#pragma unroll
        for (int k = 0; k < 6; ++k) {
            const unsigned short* p = &fscl[((size_t)k * NPX + px) * 96 + q * 8];
            short8_t a0 = *(const short8_t*)&p[0];
            short8_t a1 = *(const short8_t*)&p[32];
            short8_t a2 = *(const short8_t*)&p[64];
#pragma unroll
            for (int e = 0; e < 8; ++e) {
                s0[e] += bf2f((unsigned short)a0[e]);
                s1[e] += bf2f((unsigned short)a1[e]);
                s2[e] += bf2f((unsigned short)a2[e]);
            }
        }
#pragma unroll
        for (int e = 0; e < 8; ++e) {
            s_S[px_l * 96 + q * 8 + e]      = s1[e] * 0.2f - s0[e];
            s_S[px_l * 96 + 32 + q * 8 + e] = s0[e];
            s_S[px_l * 96 + 64 + q * 8 + e] = s2[e] * (1.f / 6.f);
        }
    }
    __syncthreads();
    for (int u = tid; u < 384; u += 256) {
        int k = u >> 6, px_l = u & 63;
        int px = px0 + px_l;
        int py = px >> 7, pxc = px & 127;
        const unsigned short* fp = &fscl[((size_t)k * NPX + px) * 96];
#pragma unroll
        for (int q = 0; q < 4; ++q) {
            short8_t f0 = *(const short8_t*)&fp[q * 8];
            short8_t f1 = *(const short8_t*)&fp[32 + q * 8];
            short8_t o0, o1, o2;
#pragma unroll
            for (int e = 0; e < 8; ++e) {
                float v0 = bf2f((unsigned short)f0[e]);
                float v1 = bf2f((unsigned short)f1[e]);
                o0[e] = (short)f2bf(s_S[px_l * 96 + q * 8 + e] + 2.f * v0);
                o1[e] = (short)f2bf(s_S[px_l * 96 + 32 + q * 8 + e] - v0 + v1);
                o2[e] = (short)f2bf(s_S[px_l * 96 + 64 + q * 8 + e]);
            }
            *(short8_t*)&fcat[((size_t)(0 * 6 + k) * NPX + px) * 32 + q * 8] = o0;
            *(short8_t*)&fcat[((size_t)(1 * 6 + k) * NPX + px) * 32 + q * 8] = o1;
            *(short8_t*)&fcat[((size_t)(2 * 6 + k) * NPX + px) * 32 + q * 8] = o2;
        }
        short8_t xz;
#pragma unroll
        for (int e = 0; e < 8; ++e) xz[e] = 0;
#pragma unroll
        for (int ch = 0; ch < 3; ++ch)
            xz[ch] = (short)f2bf(x[(size_t)(k * 3 + ch) * IMG + (size_t)(y1 + py) * Ww + x1 + pxc]);
        unsigned short* d3 = &fcat[((size_t)(3 * 6 + k) * NPX + px) * 32];
        *(short8_t*)&d3[0] = xz;
        short8_t z;
#pragma unroll
        for (int e = 0; e < 8; ++e) z[e] = 0;
        *(short8_t*)&d3[8] = z; *(short8_t*)&d3[16] = z; *(short8_t*)&d3[24] = z;
    }
}

// ---------------- merge1 MFMA: 32x16 tile, 512 thr, IC=128 (4 kc) ---------------
__global__ __launch_bounds__(512, 4) void merge1_mfma(
    const unsigned short* __restrict__ fcat, const unsigned short* __restrict__ WF,
    const float* __restrict__ m1b, unsigned short* __restrict__ h1cl)
{
    const int tid = threadIdx.x;
    const int l = tid & 63, w = tid >> 6;
    const int T = blockIdx.x;             // 32 tiles
    const int k = blockIdx.y >> 1, half = blockIdx.y & 1;
    const int ty0 = (T >> 3) * 32, tx0 = (T & 7) * 16;

    __shared__ __align__(16) unsigned short s_a[612 * AST];
    __shared__ __align__(16) unsigned short s_b[18 * 512];

    f32x4 acc[4][2];
#pragma unroll
    for (int mf = 0; mf < 4; ++mf)
#pragma unroll
        for (int nf = 0; nf < 2; ++nf) acc[mf][nf] = (f32x4){0.f, 0.f, 0.f, 0.f};

    const int colb = l & 15, qo = (l >> 4) * 8;

    for (int kc = 0; kc < 4; ++kc) {
        __syncthreads();
        const unsigned short* src_a = fcat + (size_t)(kc * 6 + k) * NPX * 32;
        for (int u = tid; u < 2448; u += 512) {
            int pxs = u >> 2, q = u & 3;
            int r = pxs / 18, c = pxs - r * 18;
            int py = ty0 - 1 + r, px = tx0 - 1 + c;
            short8_t o;
            if (py >= 0 && py < WINP && px >= 0 && px < WINP) {
                o = *(const short8_t*)&src_a[(size_t)(py * WINP + px) * 32 + q * 8];
            } else {
#pragma unroll
                for (int e = 0; e < 8; ++e) o[e] = 0;
            }
            *(short8_t*)&s_a[pxs * AST + q * 8] = o;
        }
        {
            const unsigned short* src = WF + (size_t)((108 + (half * 4 + kc) * 18)) * 512;
            for (int u = tid; u < 1152; u += 512)
                *(short8_t*)&s_b[u * 8] = *(const short8_t*)&src[u * 8];
        }
        __syncthreads();
#pragma unroll
        for (int dx = 0; dx < 3; ++dx) {
            short8_t a6[6];
#pragma unroll
            for (int i = 0; i < 6; ++i)
                a6[i] = *(const short8_t*)&s_a[((w * 4 + i) * 18 + colb + dx) * AST + qo];
#pragma unroll
            for (int dy = 0; dy < 3; ++dy)
#pragma unroll
            for (int nf = 0; nf < 2; ++nf) {
                short8_t b = *(const short8_t*)&s_b[(((dy * 3 + dx) * 2 + nf) * 64 + l) * 8];
#pragma unroll
                for (int mf = 0; mf < 4; ++mf)
                    acc[mf][nf] = __builtin_amdgcn_mfma_f32_16x16x32_bf16(a6[mf + dy], b, acc[mf][nf], 0, 0, 0);
            }
        }
    }
    __syncthreads();
    unsigned short* s_t = s_a;
#pragma unroll
    for (int nf = 0; nf < 2; ++nf) {
        float bias = m1b[half * 32 + nf * 16 + (l & 15)];
#pragma unroll
        for (int mf = 0; mf < 4; ++mf) {
            int row = w * 4 + mf;
#pragma unroll
            for (int r = 0; r < 4; ++r) {
                int colpx = (l >> 4) * 4 + r;
                float v = acc[mf][nf][r] + bias;
                v = v >= 0.f ? v : 0.2f * v;
                s_t[(row * 16 + colpx) * 32 + nf * 16 + (l & 15)] = f2bf(v);
            }
        }
    }
    __syncthreads();
    {
        int row = tid >> 4, col = tid & 15;
        size_t gpx = (size_t)(ty0 + row) * WINP + tx0 + col;
        unsigned short* dst = h1cl + ((size_t)k * NPX + gpx) * 64 + half * 32;
#pragma unroll
        for (int i = 0; i < 4; ++i)
            *(short8_t*)&dst[i * 8] = *(short8_t*)&s_t[tid * 32 + i * 8];
    }
}

// ---------------- fused merge2 + head: h2 lives in LDS --------------------------
// grid (49 = 7x7 tiles over [10,118), 6 = k), 256 thr.
__global__ __launch_bounds__(256, 1) void mergehead(
    const unsigned short* __restrict__ h1cl, const unsigned short* __restrict__ WF,
    const float* __restrict__ m2b, const float* __restrict__ hb,
    const int* __restrict__ box, float* __restrict__ out)
{
    const int tid = threadIdx.x;
    const int l = tid & 63, w = tid >> 6;
    const int T = blockIdx.x;
    const int k = blockIdx.y;
    const int oy0 = 10 + (T / 7) * 16, ox0 = 10 + (T % 7) * 16;
    const int y1 = box[0], x1 = box[1];

    __shared__ __align__(16) unsigned short s_h1[400 * H1ST];   // 20x20x64
    __shared__ __align__(16) unsigned short s_h2[324 * H1ST];   // 18x18x64
    __shared__ __align__(16) unsigned short s_b[36 * 512];

    // stage h1 (always in-bounds: rows/cols in [8,123])
    {
        const unsigned short* src = h1cl + (size_t)k * NPX * 64;
        for (int u = tid; u < 3200; u += 256) {
            int pxs = u >> 3, q = u & 7;
            int r = pxs / 20, c = pxs - r * 20;
            int py = oy0 - 2 + r, px = ox0 - 2 + c;
            *(short8_t*)&s_h1[pxs * H1ST + q * 8] =
                *(const short8_t*)&src[(size_t)(py * WINP + px) * 64 + q * 8];
        }
    }

    // merge2 over 18x18=324 px, flattened into 24 Mfrags (frag F = mf*4 + w)
    int rr[6], cc[6];
#pragma unroll
    for (int mf = 0; mf < 6; ++mf) {
        int pxb = (mf * 4 + w) * 16 + (l & 15);
        int px = pxb < 324 ? pxb : 0;
        rr[mf] = px / 18; cc[mf] = px - rr[mf] * 18;
    }
    f32x4 acc[6][4];
#pragma unroll
    for (int mf = 0; mf < 6; ++mf)
#pragma unroll
        for (int nf = 0; nf < 4; ++nf) acc[mf][nf] = (f32x4){0.f, 0.f, 0.f, 0.f};

    const int qo = (l >> 4) * 8;
    for (int kc = 0; kc < 2; ++kc) {
        __syncthreads();
        for (int u = tid; u < 2304; u += 256) {
            int f = u >> 6, within = u & 63;
            int tap = f >> 2, nf = f & 3;
            int srcfrag = 252 + ((nf >> 1) * 2 + kc) * 18 + tap * 2 + (nf & 1);
            *(short8_t*)&s_b[(size_t)f * 512 + within * 8] =
                *(const short8_t*)&WF[(size_t)srcfrag * 512 + within * 8];
        }
        __syncthreads();
#pragma unroll
        for (int tap = 0; tap < 9; ++tap) {
            int dy = tap / 3, dx = tap % 3;
            short8_t a[6];
#pragma unroll
            for (int mf = 0; mf < 6; ++mf)
                a[mf] = *(const short8_t*)&s_h1[((rr[mf] + dy) * 20 + cc[mf] + dx) * H1ST + kc * 32 + qo];
#pragma unroll
            for (int nf = 0; nf < 4; ++nf) {
                short8_t b = *(const short8_t*)&s_b[((tap * 4 + nf) * 64 + l) * 8];
#pragma unroll
                for (int mf = 0; mf < 6; ++mf)
                    acc[mf][nf] = __builtin_amdgcn_mfma_f32_16x16x32_bf16(a[mf], b, acc[mf][nf], 0, 0, 0);
            }
        }
    }
    __syncthreads();   // all merge2 reads of s_h1/s_b done
#pragma unroll
    for (int nf = 0; nf < 4; ++nf) {
        float bias = m2b[nf * 16 + (l & 15)];
#pragma unroll
        for (int mf = 0; mf < 6; ++mf) {
#pragma unroll
            for (int r = 0; r < 4; ++r) {
                int px = (mf * 4 + w) * 16 + (l >> 4) * 4 + r;
                if (px < 324)
                    s_h2[px * H1ST + nf * 16 + (l & 15)] = f2bf(acc[mf][nf][r] + bias);
            }
        }
    }
    for (int u = tid; u < 1152; u += 256)
        *(short8_t*)&s_b[u * 8] = *(const short8_t*)&WF[(size_t)324 * 512 + u * 8];
    __syncthreads();

    // head over 16x16 tile
    f32x4 acc2[4];
#pragma unroll
    for (int mf = 0; mf < 4; ++mf) acc2[mf] = (f32x4){0.f, 0.f, 0.f, 0.f};
#pragma unroll
    for (int kc = 0; kc < 2; ++kc)
#pragma unroll
    for (int tap = 0; tap < 9; ++tap) {
        int dy = tap / 3, dx = tap % 3;
        short8_t b = *(const short8_t*)&s_b[((kc * 9 + tap) * 64 + l) * 8];
#pragma unroll
        for (int mf = 0; mf < 4; ++mf) {
            short8_t a = *(const short8_t*)&s_h2[((w * 4 + mf + dy) * 18 + (l & 15) + dx) * H1ST + kc * 32 + qo];
            acc2[mf] = __builtin_amdgcn_mfma_f32_16x16x32_bf16(a, b, acc2[mf], 0, 0, 0);
        }
    }
    int oc = l & 15;
    if (oc < 3) {
        float bias = hb[oc];
#pragma unroll
        for (int mf = 0; mf < 4; ++mf) {
            int orow = oy0 + w * 4 + mf;
            if (orow < 118) {
#pragma unroll
                for (int r = 0; r < 4; ++r) {
                    int ocol = ox0 + (l >> 4) * 4 + r;
                    if (ocol < 118) {
                        float v = (tanhf(acc2[mf][r] + bias) + 1.0f) * 0.5f;
                        out[(size_t)(k * 3 + oc) * IMG + (size_t)(y1 + orow) * Ww + x1 + ocol] = v;
                    }
                }
            }
        }
    }
}

extern "C" void kernel_launch(void* const* d_in, const int* in_sizes, int n_in,
                              void* d_out, int out_size, void* d_ws, size_t ws_size,
                              hipStream_t stream)
{
    const float* x       = (const float*)d_in[0];
    const float* pred    = (const float*)d_in[1];
    const float* feat    = (const float*)d_in[2];
    const float* split_w = (const float*)d_in[3];
    const float* split_b = (const float*)d_in[4];
    const float* m1w     = (const float*)d_in[5];
    const float* m1b     = (const float*)d_in[6];
    const float* m2w     = (const float*)d_in[7];
    const float* m2b     = (const float*)d_in[8];
    const float* hw      = (const float*)d_in[9];
    const float* hb      = (const float*)d_in[10];
    float* out = (float*)d_out;

    char* base = (char*)d_ws;
    size_t o = 0;
    int* box = (int*)(base + o);                           o += 256;
    unsigned short* WF = (unsigned short*)(base + o);      o += (size_t)175104 * 2;  o = (o + 255) & ~(size_t)255;
    unsigned short* msplit = (unsigned short*)(base + o);  o += (size_t)36 * NPX * 32 * 2;
    unsigned short* fscl = (unsigned short*)(base + o);    o += (size_t)6 * NPX * 96 * 2;
    unsigned short* fcat = (unsigned short*)(base + o);    o += (size_t)24 * NPX * 32 * 2;
    unsigned short* h1cl = (unsigned short*)(base + o);    o += (size_t)6 * NPX * 64 * 2;

    box_kernel<<<1, 256, 0, stream>>>(pred, box);
    prep_all<<<14508, 256, 0, stream>>>(split_w, m1w, m2w, hw, WF,
                                        (const float4*)pred, (float4*)out,
                                        feat, pred, box, msplit);

    for (int it = 0; it < 2; ++it) {
        split_mfma<<<dim3(32, 18), 512, 0, stream>>>(msplit, WF, split_b, fscl);
        combine_kernel<<<256, 256, 0, stream>>>(fscl, x, box, fcat);
        merge1_mfma<<<dim3(32, 12), 512, 0, stream>>>(fcat, WF, m1b, h1cl);
        mergehead<<<dim3(49, 6), 256, 0, stream>>>(h1cl, WF, m2b, hb, box, out);
        if (it == 0)
            modulate_kernel<<<9216, 256, 0, stream>>>(feat, out, box, msplit);
    }
}